// Round 7
// baseline (142.812 us; speedup 1.0000x reference)
//
#include <hip/hip_runtime.h>

// B=16, T=2048, C=200, H=64 attention head with padding mask.
// Round 7: (a) attn: 128 queries/wave (8 m-tiles) -> L1-return bytes halve again
// (268->134 MB; the confirmed binding pipe r3->r4->r5). 1 block/CU, 1 wave/SIMD,
// ILP-hidden latency (barrier-free K-loop). (b) qkv: prep_w fused away — each block
// repacks raw fp32 W into LDS itself (W is L2-resident). 2 kernels total.
// NOTE: ~58us of dur_us is harness overhead in-window (256MiB 0xAA ws poison ~46us
// + ~39MB input restore ~12us) — untouchable floor.

typedef __attribute__((ext_vector_type(8))) __bf16 bf16x8;
typedef __attribute__((ext_vector_type(4))) __bf16 bf16x4;
typedef __attribute__((ext_vector_type(4))) float f32x4;

#define T_SEQ 2048
#define C_DIM 200
#define H_DIM 64
#define BT_TOT 32768
#define QKV_ELEMS 2097152
#define PPAD 72            // P row pad (bf16): 2-way bank alias only (free)
#define OPAD 68            // combine row pad (f32)
#define LOG2E 1.44269504088896f

// ---------------- Kernel 1: QKV projection, fused weight repack ----------------
// grid = 512 blocks x 256 threads (4 waves x 16 rows = 64 rows/block).
// Each block repacks raw fp32 W{q,k,v} -> LDS in MFMA fragment order (two 48KB-max
// phases), then computes. Wq scaled by H^-0.5*log2(e) so scores land in log2 domain.
// Fragment layout (phase-local chunk c): full chunk (ks,w,t) at ((ks*12+w*4+t)<<9),
// elem lane*8+j = W_w[c=ks*32+(lane>>4)*8+j][h=t*16+(lane&15)]; ks=6 compact chunk
// (w,t) at 12288+((w*4+t)<<7): elem l15*8+j = W_w[c=192+j][h=t*16+l15].
__global__ __launch_bounds__(256) void qkv_proj(const float* __restrict__ Wk,
                                                const float* __restrict__ Wq,
                                                const float* __restrict__ Wv,
                                                const float* __restrict__ x,
                                                __bf16* __restrict__ qb,
                                                __bf16* __restrict__ kb,
                                                __bf16* __restrict__ vT) {
    __shared__ __bf16 Wl[24576];  // 48 KB; phase B + transpose epilogue reuse it

    const int tid = threadIdx.x;
    const int wave = tid >> 6, lane = tid & 63, l15 = lane & 15, quad = lane >> 4;
    const int m0b = blockIdx.x * 64;
    const int row0 = m0b + wave * 16;

    f32x4 acc[3][4] = {};  // [w][h-tile], 16 rows per wave

    // ---- phase A: repack c 0..127 (ks 0..3) ----
    #pragma unroll
    for (int w = 0; w < 3; ++w) {
        const float* W = (w == 0) ? Wq : (w == 1) ? Wk : Wv;
        const float scale = (w == 0) ? 0.125f * LOG2E : 1.f;
        for (int i = tid; i < 8192; i += 256) {
            const int c = i >> 6, h = i & 63;
            const float val = W[i] * scale;
            const int ks = c >> 5, cq = (c >> 3) & 3, j = c & 7;
            const int t = h >> 4, hl = h & 15;
            Wl[((ks * 12 + w * 4 + t) << 9) + (cq * 16 + hl) * 8 + j] = (__bf16)val;
        }
    }
    __syncthreads();
    #pragma unroll
    for (int ks = 0; ks < 4; ++ks) {
        const float* xr = x + (size_t)(row0 + l15) * C_DIM + ks * 32 + quad * 8;
        const float4 f0 = *(const float4*)xr;
        const float4 f1 = *(const float4*)(xr + 4);
        bf16x8 a;
        a[0]=(__bf16)f0.x; a[1]=(__bf16)f0.y; a[2]=(__bf16)f0.z; a[3]=(__bf16)f0.w;
        a[4]=(__bf16)f1.x; a[5]=(__bf16)f1.y; a[6]=(__bf16)f1.z; a[7]=(__bf16)f1.w;
        #pragma unroll
        for (int w = 0; w < 3; ++w)
            #pragma unroll
            for (int t = 0; t < 4; ++t) {
                const bf16x8 bf = *(const bf16x8*)(Wl + ((ks * 12 + w * 4 + t) << 9) + lane * 8);
                acc[w][t] = __builtin_amdgcn_mfma_f32_16x16x32_bf16(a, bf, acc[w][t], 0, 0, 0);
            }
    }
    __syncthreads();

    // ---- phase B: repack c 128..199 (ks 4,5 full; ks 6 compact) ----
    #pragma unroll
    for (int w = 0; w < 3; ++w) {
        const float* W = (w == 0) ? Wq : (w == 1) ? Wk : Wv;
        const float scale = (w == 0) ? 0.125f * LOG2E : 1.f;
        for (int i = tid; i < 4608; i += 256) {
            const int c = 128 + (i >> 6), h = i & 63;
            const float val = W[c * H_DIM + h] * scale;
            const int t = h >> 4, hl = h & 15;
            int addr;
            if (c < 192) {
                const int ks = c >> 5, cq = (c >> 3) & 3, j = c & 7;
                addr = (((ks - 4) * 12 + w * 4 + t) << 9) + (cq * 16 + hl) * 8 + j;
            } else {
                addr = 12288 + ((w * 4 + t) << 7) + hl * 8 + (c - 192);
            }
            Wl[addr] = (__bf16)val;
        }
    }
    __syncthreads();
    #pragma unroll
    for (int ks = 4; ks < 7; ++ks) {
        bf16x8 a;
        if (ks < 6 || quad == 0) {
            // ks=6,quad0 reads c 192..199 exactly (in-bounds); other quads c>=200 -> A=0
            const float* xr = x + (size_t)(row0 + l15) * C_DIM + ks * 32 + quad * 8;
            const float4 f0 = *(const float4*)xr;
            const float4 f1 = *(const float4*)(xr + 4);
            a[0]=(__bf16)f0.x; a[1]=(__bf16)f0.y; a[2]=(__bf16)f0.z; a[3]=(__bf16)f0.w;
            a[4]=(__bf16)f1.x; a[5]=(__bf16)f1.y; a[6]=(__bf16)f1.z; a[7]=(__bf16)f1.w;
        } else {
            #pragma unroll
            for (int j = 0; j < 8; ++j) a[j] = (__bf16)0.f;
        }
        #pragma unroll
        for (int w = 0; w < 3; ++w)
            #pragma unroll
            for (int t = 0; t < 4; ++t) {
                // ks=6: compact chunk; quads 1..3 read quad0's data -> harmless (A rows 0)
                const int off = (ks < 6) ? (((ks - 4) * 12 + w * 4 + t) << 9) + lane * 8
                                         : 12288 + ((w * 4 + t) << 7) + l15 * 8;
                const bf16x8 bf = *(const bf16x8*)(Wl + off);
                acc[w][t] = __builtin_amdgcn_mfma_f32_16x16x32_bf16(a, bf, acc[w][t], 0, 0, 0);
            }
    }

    // ---- epilogue: q,k direct stores; vT via LDS transpose for coalesced b128 ----
    #pragma unroll
    for (int t = 0; t < 4; ++t)
        #pragma unroll
        for (int r = 0; r < 4; ++r) {
            const size_t m = row0 + quad * 4 + r;
            qb[m * H_DIM + t * 16 + l15] = (__bf16)acc[0][t][r];
            kb[m * H_DIM + t * 16 + l15] = (__bf16)acc[1][t][r];
        }
    __syncthreads();
    #pragma unroll
    for (int t = 0; t < 4; ++t)
        #pragma unroll
        for (int r = 0; r < 4; ++r)
            Wl[(t * 16 + l15) * 72 + wave * 16 + quad * 4 + r] = (__bf16)acc[2][t][r];
    __syncthreads();
    const int bb = m0b >> 11, tloc = m0b & 2047;
    #pragma unroll
    for (int i = 0; i < 2; ++i) {
        const int seg = i * 256 + tid;          // 512 segs: h row, 8-elem column chunk
        const int h = seg >> 3, s8 = seg & 7;
        *(bf16x8*)(vT + ((size_t)bb * H_DIM + h) * T_SEQ + tloc + s8 * 8) =
            *(const bf16x8*)(Wl + h * 72 + s8 * 8);
    }
}

// ---------------- Kernel 2: attention, 128 queries/wave ----------------
// grid = (T/128, B) = 256 blocks (1/CU); block = 256 (4 waves = 4 key-splits of 512,
// all over the same 128-q tile). No-max softmax in log2 domain (S~N(0,1): fp32-safe;
// masked keys -> exp2(-1e30) = exact 0). Barrier-free K-loop; 1 wave/SIMD, ILP-hidden.
__global__ __launch_bounds__(256, 1) void attn(const __bf16* __restrict__ qb,
                                               const __bf16* __restrict__ kb,
                                               const __bf16* __restrict__ vT,
                                               const int* __restrict__ pm,
                                               float* __restrict__ out) {
    // arena: [0,8K) key bias f32[2048]; [8K,+73728) per-wave P (4 x 128 x PPAD bf16),
    // unioned with combine region Ocomb[128][OPAD] f32 + Lcomb[128] f32.
    __shared__ __align__(16) char arena[8192 + 73728];
    float* biasS = (float*)arena;

    const int tid = threadIdx.x;
    const int wave = tid >> 6, lane = tid & 63, l15 = lane & 15, quad = lane >> 4;
    const int ks = wave;
    const int b = blockIdx.y;
    const int q0 = blockIdx.x * 128;
    const size_t bT = (size_t)b * T_SEQ;

    for (int i = tid; i < 512; i += 256) {
        const int4 p4 = *(const int4*)(pm + bT + i * 4);
        biasS[i * 4 + 0] = p4.x ? 0.f : -1e30f;
        biasS[i * 4 + 1] = p4.y ? 0.f : -1e30f;
        biasS[i * 4 + 2] = p4.z ? 0.f : -1e30f;
        biasS[i * 4 + 3] = p4.w ? 0.f : -1e30f;
    }
    __syncthreads();

    // Q fragments: qa[mt][s], lane holds Q[q0+mt*16+l15][s*32+quad*8 ..+8]
    bf16x8 qa[8][2];
    #pragma unroll
    for (int mt = 0; mt < 8; ++mt)
        #pragma unroll
        for (int s = 0; s < 2; ++s)
            qa[mt][s] = *(const bf16x8*)(qb + (bT + q0 + mt * 16 + l15) * H_DIM + s * 32 + quad * 8);

    __bf16* P = (__bf16*)(arena + 8192) + wave * (128 * PPAD);
    const __bf16* kbase = kb + bT * H_DIM;
    const __bf16* vbase = vT + (size_t)b * H_DIM * T_SEQ;

    f32x4 oacc[8][4] = {};   // O'[qtile][h-tile][row=quad*4+r]
    float lsum[8] = {};

    for (int kt = 0; kt < 8; ++kt) {
        const int key0 = ks * 512 + kt * 64;

        // S'^T per n-block: 8 q-tiles share each K fragment; exp; P -> LDS
        #pragma unroll
        for (int n = 0; n < 4; ++n) {
            const f32x4 bias = *(const f32x4*)(biasS + key0 + n * 16 + quad * 4);
            bf16x8 kf[2];
            #pragma unroll
            for (int s = 0; s < 2; ++s)
                kf[s] = *(const bf16x8*)(kbase + (key0 + n * 16 + l15) * H_DIM + s * 32 + quad * 8);
            f32x4 s_[8];
            #pragma unroll
            for (int mt = 0; mt < 8; ++mt) s_[mt] = bias;
            #pragma unroll
            for (int s = 0; s < 2; ++s)
                #pragma unroll
                for (int mt = 0; mt < 8; ++mt)
                    s_[mt] = __builtin_amdgcn_mfma_f32_16x16x32_bf16(kf[s], qa[mt][s], s_[mt], 0, 0, 0);
            #pragma unroll
            for (int mt = 0; mt < 8; ++mt) {
                bf16x4 p4;
                #pragma unroll
                for (int r = 0; r < 4; ++r) {
                    const float e = exp2f(s_[mt][r]);
                    lsum[mt] += e;
                    p4[r] = (__bf16)e;
                }
                *(bf16x4*)(P + (mt * 16 + l15) * PPAD + n * 16 + quad * 4) = p4;
            }
        }

        // re-read P as A-operand (per-wave buffer; DS in-order within wave -> no barrier)
        bf16x8 pa[8][2];
        #pragma unroll
        for (int mt = 0; mt < 8; ++mt)
            #pragma unroll
            for (int s = 0; s < 2; ++s)
                pa[mt][s] = *(const bf16x8*)(P + (mt * 16 + l15) * PPAD + s * 32 + quad * 8);

        // O' += P V, V fragment shared across 8 q-tiles
        #pragma unroll
        for (int t = 0; t < 4; ++t) {
            bf16x8 vf[2];
            #pragma unroll
            for (int s = 0; s < 2; ++s)
                vf[s] = *(const bf16x8*)(vbase + (size_t)(t * 16 + l15) * T_SEQ + key0 + s * 32 + quad * 8);
            #pragma unroll
            for (int s = 0; s < 2; ++s)
                #pragma unroll
                for (int mt = 0; mt < 8; ++mt)
                    oacc[mt][t] = __builtin_amdgcn_mfma_f32_16x16x32_bf16(pa[mt][s], vf[s], oacc[mt][t], 0, 0, 0);
        }
    }

    #pragma unroll
    for (int mt = 0; mt < 8; ++mt) {
        lsum[mt] += __shfl_xor(lsum[mt], 16, 64);
        lsum[mt] += __shfl_xor(lsum[mt], 32, 64);
    }

    // in-LDS combine: waves 1,2,3,0 accumulate sequentially, then ALL waves finalize
    // 2 m-tiles each from LDS (parallel epilogue; l read is a broadcast, no shuffles).
    float* Ocomb = (float*)(arena + 8192);   // [128][OPAD]
    float* Lcomb = Ocomb + 128 * OPAD;       // [128]

    __syncthreads();
    #pragma unroll
    for (int step = 0; step < 4; ++step) {
        const int who = (step == 3) ? 0 : step + 1;  // order: ks1, ks2, ks3, ks0
        if (ks == who) {
            #pragma unroll
            for (int mt = 0; mt < 8; ++mt) {
                if (step == 0) {
                    #pragma unroll
                    for (int t = 0; t < 4; ++t)
                        #pragma unroll
                        for (int r = 0; r < 4; ++r)
                            Ocomb[(mt * 16 + quad * 4 + r) * OPAD + t * 16 + l15] = oacc[mt][t][r];
                    if (quad == 0) Lcomb[mt * 16 + l15] = lsum[mt];
                } else {
                    #pragma unroll
                    for (int t = 0; t < 4; ++t)
                        #pragma unroll
                        for (int r = 0; r < 4; ++r)
                            Ocomb[(mt * 16 + quad * 4 + r) * OPAD + t * 16 + l15] += oacc[mt][t][r];
                    if (quad == 0) Lcomb[mt * 16 + l15] += lsum[mt];
                }
            }
        }
        __syncthreads();
    }

    // parallel finalize: wave ks handles m-tiles 2ks, 2ks+1
    #pragma unroll
    for (int mi = 0; mi < 2; ++mi) {
        const int mt = ks * 2 + mi;
        #pragma unroll
        for (int r = 0; r < 4; ++r) {
            const int qpos = q0 + mt * 16 + quad * 4 + r;
            const float lv = Lcomb[mt * 16 + quad * 4 + r];       // broadcast LDS read
            const bool qvalid = biasS[qpos] == 0.f;               // query mask == pm[b][t]
            const float inv = (qvalid && lv > 0.f) ? 1.f / lv : 0.f;
            #pragma unroll
            for (int t = 0; t < 4; ++t)
                out[(bT + qpos) * H_DIM + t * 16 + l15] =
                    Ocomb[(mt * 16 + quad * 4 + r) * OPAD + t * 16 + l15] * inv;
        }
    }
}

extern "C" void kernel_launch(void* const* d_in, const int* in_sizes, int n_in,
                              void* d_out, int out_size, void* d_ws, size_t ws_size,
                              hipStream_t stream) {
    const float* x  = (const float*)d_in[0];
    const int* pm   = (const int*)d_in[1];
    const float* Wk = (const float*)d_in[2];
    const float* Wq = (const float*)d_in[3];
    const float* Wv = (const float*)d_in[4];
    float* out = (float*)d_out;

    // ws: qb | kb | vT (bf16, 4MB each)
    __bf16* qb = (__bf16*)d_ws;
    __bf16* kb = qb + QKV_ELEMS;
    __bf16* vT = kb + QKV_ELEMS;

    qkv_proj<<<dim3(BT_TOT / 64), dim3(256), 0, stream>>>(Wk, Wq, Wv, x, qb, kb, vT);
    attn<<<dim3(T_SEQ / 128, 16), dim3(256), 0, stream>>>(qb, kb, vT, pm, out);
}